// Round 2
// baseline (374.440 us; speedup 1.0000x reference)
//
#include <hip/hip_runtime.h>

#define B 32
#define C 512
#define TP 1024
#define CHUNK 32

// Kernel 1: per-batch inclusive cumsum of durations (1024 int32 each).
// 256 threads: int4 load -> serial 4-scan -> wave shuffle scan -> combine 4 waves.
__global__ void __launch_bounds__(256) cumsum_k(const int* __restrict__ dur,
                                                int* __restrict__ cum) {
    const int b = blockIdx.x, tid = threadIdx.x;
    const int lane = tid & 63, wid = tid >> 6;
    int4 v = ((const int4*)(dur + b * TP))[tid];
    const int s1 = v.x + v.y, s2 = s1 + v.z, s3 = s2 + v.w;
    int val = s3;
    #pragma unroll
    for (int off = 1; off < 64; off <<= 1) {
        int n = __shfl_up(val, off, 64);
        if (lane >= off) val += n;
    }
    __shared__ int wtot[4];
    if (lane == 63) wtot[wid] = val;
    __syncthreads();
    int base = 0;
    #pragma unroll
    for (int w = 0; w < 4; ++w)
        if (w < wid) base += wtot[w];
    const int excl = base + val - s3;   // exclusive prefix for this thread's 4
    int4 o;
    o.x = excl + v.x; o.y = excl + s1; o.z = excl + s2; o.w = excl + s3;
    ((int4*)(cum + b * TP))[tid] = o;
}

// Kernel 2: one binary search per (b, t) -> phone index (-1 if invalid) + mask.
__global__ void __launch_bounds__(256) phone_k(const int* __restrict__ cum,
                                               int* __restrict__ pidx,
                                               float* __restrict__ mask,
                                               int MF) {
    __shared__ int scum[TP];
    const int b = blockIdx.y;
    for (int i = threadIdx.x; i < TP; i += 256) scum[i] = cum[b * TP + i];
    __syncthreads();
    const int t = blockIdx.x * 256 + threadIdx.x;
    if (t >= MF) return;
    const int total = scum[TP - 1];
    int lo = 0, hi = TP;
    while (lo < hi) {
        int mid = (lo + hi) >> 1;
        if (scum[mid] <= t) lo = mid + 1; else hi = mid;
    }
    const bool valid = (t < total);
    pidx[(size_t)b * MF + t] = valid ? (lo < TP - 1 ? lo : TP - 1) : -1;
    mask[(size_t)b * MF + t] = valid ? 0.0f : 1.0f;
}

// Kernel 3: pure streaming gather. No LDS, no search. Each thread handles
// 4 t's spaced 256 apart (block covers 1024 t's) so every store instruction
// stays lane-dense. 32 channels per block via grid.z -> 8192 waves (32/CU).
__global__ void __launch_bounds__(256) gather_k(const float* __restrict__ x,
                                                const int* __restrict__ pidx,
                                                float* __restrict__ out,
                                                int MF) {
    const int b = blockIdx.y, z = blockIdx.z;
    const int tbase = blockIdx.x * 1024 + threadIdx.x;
    const int* pb = pidx + (size_t)b * MF;

    int t[4], p[4], q[4];
    #pragma unroll
    for (int j = 0; j < 4; ++j) {
        t[j] = tbase + j * 256;
        p[j] = (t[j] < MF) ? pb[t[j]] : -2;   // -2: out of range, skip store
        q[j] = p[j] >= 0 ? p[j] : 0;          // safe load index
    }

    const float* xb = x   + ((size_t)b * C + (size_t)z * CHUNK) * TP;
    float*       ob = out + ((size_t)b * C + (size_t)z * CHUNK) * MF;

    #pragma unroll 2
    for (int c = 0; c < CHUNK; ++c) {
        const float* xr = xb + (size_t)c * TP;
        float* orow     = ob + (size_t)c * MF;
        #pragma unroll
        for (int j = 0; j < 4; ++j) {
            if (p[j] != -2) {
                float v = xr[q[j]];
                orow[t[j]] = (p[j] >= 0) ? v : 0.0f;
            }
        }
    }
}

extern "C" void kernel_launch(void* const* d_in, const int* in_sizes, int n_in,
                              void* d_out, int out_size, void* d_ws, size_t ws_size,
                              hipStream_t stream) {
    const float* x   = (const float*)d_in[0];
    const int*   dur = (const int*)d_in[1];
    float* out = (float*)d_out;

    // out_size = B*C*MF + B*MF = B*(C+1)*MF
    const int MF = out_size / (B * (C + 1));
    float* mask = out + (size_t)B * C * MF;

    int* cum  = (int*)d_ws;            // B*TP ints = 128 KB
    int* pidx = cum + (size_t)B * TP;  // B*MF ints (<= 1 MB)

    cumsum_k<<<B, 256, 0, stream>>>(dur, cum);

    dim3 pgrid((MF + 255) / 256, B);
    phone_k<<<pgrid, 256, 0, stream>>>(cum, pidx, mask, MF);

    dim3 ggrid((MF + 1023) / 1024, B, C / CHUNK);
    gather_k<<<ggrid, 256, 0, stream>>>(x, pidx, out, MF);
}

// Round 3
// 359.082 us; speedup vs baseline: 1.0428x; 1.0428x over previous
//
#include <hip/hip_runtime.h>

#define B 32
#define C 512
#define TP 1024
#define CHUNK 32

// Kernel 1: per-batch inclusive cumsum of durations (1024 int32 each).
__global__ void __launch_bounds__(256) cumsum_k(const int* __restrict__ dur,
                                                int* __restrict__ cum) {
    const int b = blockIdx.x, tid = threadIdx.x;
    const int lane = tid & 63, wid = tid >> 6;
    int4 v = ((const int4*)(dur + b * TP))[tid];
    const int s1 = v.x + v.y, s2 = s1 + v.z, s3 = s2 + v.w;
    int val = s3;
    #pragma unroll
    for (int off = 1; off < 64; off <<= 1) {
        int n = __shfl_up(val, off, 64);
        if (lane >= off) val += n;
    }
    __shared__ int wtot[4];
    if (lane == 63) wtot[wid] = val;
    __syncthreads();
    int base = 0;
    #pragma unroll
    for (int w = 0; w < 4; ++w)
        if (w < wid) base += wtot[w];
    const int excl = base + val - s3;
    int4 o;
    o.x = excl + v.x; o.y = excl + s1; o.z = excl + s2; o.w = excl + s3;
    ((int4*)(cum + b * TP))[tid] = o;
}

// Kernel 2 (fused search + gather + mask): each thread owns 4 CONSECUTIVE t,
// does one binary search + linear advance, then per channel does 4 gather
// loads + ONE float4 store (1 KB per wave store instruction).
template <bool VEC>
__global__ void __launch_bounds__(256) gather_k(const float* __restrict__ x,
                                                const int* __restrict__ cum,
                                                float* __restrict__ out,
                                                float* __restrict__ mask,
                                                int MF) {
    __shared__ int scum[TP];
    const int b = blockIdx.y, z = blockIdx.z;
    ((int4*)scum)[threadIdx.x] = ((const int4*)(cum + b * TP))[threadIdx.x];
    __syncthreads();

    const int t0 = blockIdx.x * 1024 + threadIdx.x * 4;
    if (t0 >= MF) return;
    const int total = scum[TP - 1];

    // searchsorted(cum, t0, 'right'), then linear advance for t0+1..3
    int lo = 0, hi = TP;
    while (lo < hi) {
        int mid = (lo + hi) >> 1;
        if (scum[mid] <= t0) lo = mid + 1; else hi = mid;
    }
    int q[4]; bool val[4];
    int pc = lo;
    #pragma unroll
    for (int j = 0; j < 4; ++j) {
        const int tj = t0 + j;
        while (pc < TP && scum[pc] <= tj) ++pc;
        q[j] = pc < TP - 1 ? pc : TP - 1;
        val[j] = (tj < total) && (tj < MF);
    }

    const bool full = VEC && (t0 + 4 <= MF);

    if (z == 0) {  // mel_mask = ~(t < total)
        float m[4];
        #pragma unroll
        for (int j = 0; j < 4; ++j) m[j] = (t0 + j < total) ? 0.0f : 1.0f;
        float* mrow = mask + (size_t)b * MF + t0;
        if (full) {
            *(float4*)mrow = make_float4(m[0], m[1], m[2], m[3]);
        } else {
            #pragma unroll
            for (int j = 0; j < 4; ++j)
                if (t0 + j < MF) mrow[j] = m[j];
        }
    }

    const float* xb = x   + ((size_t)b * C + (size_t)z * CHUNK) * TP;
    float*       ob = out + ((size_t)b * C + (size_t)z * CHUNK) * MF;

    #pragma unroll 2
    for (int c = 0; c < CHUNK; ++c) {
        const float* xr = xb + (size_t)c * TP;
        float l0 = xr[q[0]], l1 = xr[q[1]], l2 = xr[q[2]], l3 = xr[q[3]];
        float4 v;
        v.x = val[0] ? l0 : 0.0f;
        v.y = val[1] ? l1 : 0.0f;
        v.z = val[2] ? l2 : 0.0f;
        v.w = val[3] ? l3 : 0.0f;
        float* orow = ob + (size_t)c * MF + t0;
        if (full) {
            *(float4*)orow = v;
        } else {
            const float vv[4] = {v.x, v.y, v.z, v.w};
            #pragma unroll
            for (int j = 0; j < 4; ++j)
                if (t0 + j < MF) orow[j] = vv[j];
        }
    }
}

extern "C" void kernel_launch(void* const* d_in, const int* in_sizes, int n_in,
                              void* d_out, int out_size, void* d_ws, size_t ws_size,
                              hipStream_t stream) {
    const float* x   = (const float*)d_in[0];
    const int*   dur = (const int*)d_in[1];
    float* out = (float*)d_out;

    // out_size = B*C*MF + B*MF = B*(C+1)*MF
    const int MF = out_size / (B * (C + 1));
    float* mask = out + (size_t)B * C * MF;

    int* cum = (int*)d_ws;  // B*TP ints = 128 KB scratch

    cumsum_k<<<B, 256, 0, stream>>>(dur, cum);

    dim3 ggrid((MF + 1023) / 1024, B, C / CHUNK);
    if ((MF & 3) == 0)
        gather_k<true><<<ggrid, 256, 0, stream>>>(x, cum, out, mask, MF);
    else
        gather_k<false><<<ggrid, 256, 0, stream>>>(x, cum, out, mask, MF);
}

// Round 5
// 324.139 us; speedup vs baseline: 1.1552x; 1.1078x over previous
//
#include <hip/hip_runtime.h>

#define B 32
#define C 512
#define TP 1024
#define CHUNK 32

typedef float f4 __attribute__((ext_vector_type(4)));

// Kernel 1: per-batch inclusive cumsum of durations (1024 int32 each).
__global__ void __launch_bounds__(256) cumsum_k(const int* __restrict__ dur,
                                                int* __restrict__ cum) {
    const int b = blockIdx.x, tid = threadIdx.x;
    const int lane = tid & 63, wid = tid >> 6;
    int4 v = ((const int4*)(dur + b * TP))[tid];
    const int s1 = v.x + v.y, s2 = s1 + v.z, s3 = s2 + v.w;
    int val = s3;
    #pragma unroll
    for (int off = 1; off < 64; off <<= 1) {
        int n = __shfl_up(val, off, 64);
        if (lane >= off) val += n;
    }
    __shared__ int wtot[4];
    if (lane == 63) wtot[wid] = val;
    __syncthreads();
    int base = 0;
    #pragma unroll
    for (int w = 0; w < 4; ++w)
        if (w < wid) base += wtot[w];
    const int excl = base + val - s3;
    int4 o;
    o.x = excl + v.x; o.y = excl + s1; o.z = excl + s2; o.w = excl + s3;
    ((int4*)(cum + b * TP))[tid] = o;
}

// Kernel 2 (fused search + gather + mask). Each thread owns 4 consecutive t:
// one binary search + linear advance, then per channel 4 gather loads + one
// NONTEMPORAL float4 store (bypass L2 write-allocate: out lines are never
// read, RFO fetches were doubling our write traffic).
template <bool VEC>
__global__ void __launch_bounds__(256) gather_k(const float* __restrict__ x,
                                                const int* __restrict__ cum,
                                                float* __restrict__ out,
                                                float* __restrict__ mask,
                                                int MF) {
    __shared__ int scum[TP];
    const int b = blockIdx.y, z = blockIdx.z;
    ((int4*)scum)[threadIdx.x] = ((const int4*)(cum + b * TP))[threadIdx.x];
    __syncthreads();

    const int t0 = blockIdx.x * 1024 + threadIdx.x * 4;
    if (t0 >= MF) return;
    const int total = scum[TP - 1];

    // searchsorted(cum, t0, 'right'), then linear advance for t0+1..3
    int lo = 0, hi = TP;
    while (lo < hi) {
        int mid = (lo + hi) >> 1;
        if (scum[mid] <= t0) lo = mid + 1; else hi = mid;
    }
    int q[4]; bool val[4];
    int pc = lo;
    #pragma unroll
    for (int j = 0; j < 4; ++j) {
        const int tj = t0 + j;
        while (pc < TP && scum[pc] <= tj) ++pc;
        q[j] = pc < TP - 1 ? pc : TP - 1;
        val[j] = (tj < total) && (tj < MF);
    }

    const bool full = VEC && (t0 + 4 <= MF);

    if (z == 0) {  // mel_mask = ~(t < total)
        float m[4];
        #pragma unroll
        for (int j = 0; j < 4; ++j) m[j] = (t0 + j < total) ? 0.0f : 1.0f;
        float* mrow = mask + (size_t)b * MF + t0;
        if (full) {
            f4 mv = {m[0], m[1], m[2], m[3]};
            __builtin_nontemporal_store(mv, (f4*)mrow);
        } else {
            #pragma unroll
            for (int j = 0; j < 4; ++j)
                if (t0 + j < MF) __builtin_nontemporal_store(m[j], mrow + j);
        }
    }

    const float* xb = x   + ((size_t)b * C + (size_t)z * CHUNK) * TP;
    float*       ob = out + ((size_t)b * C + (size_t)z * CHUNK) * MF;

    #pragma unroll 2
    for (int c = 0; c < CHUNK; ++c) {
        const float* xr = xb + (size_t)c * TP;
        float l0 = xr[q[0]], l1 = xr[q[1]], l2 = xr[q[2]], l3 = xr[q[3]];
        f4 v;
        v.x = val[0] ? l0 : 0.0f;
        v.y = val[1] ? l1 : 0.0f;
        v.z = val[2] ? l2 : 0.0f;
        v.w = val[3] ? l3 : 0.0f;
        float* orow = ob + (size_t)c * MF + t0;
        if (full) {
            __builtin_nontemporal_store(v, (f4*)orow);
        } else {
            const float vv[4] = {v.x, v.y, v.z, v.w};
            #pragma unroll
            for (int j = 0; j < 4; ++j)
                if (t0 + j < MF) __builtin_nontemporal_store(vv[j], orow + j);
        }
    }
}

extern "C" void kernel_launch(void* const* d_in, const int* in_sizes, int n_in,
                              void* d_out, int out_size, void* d_ws, size_t ws_size,
                              hipStream_t stream) {
    const float* x   = (const float*)d_in[0];
    const int*   dur = (const int*)d_in[1];
    float* out = (float*)d_out;

    // out_size = B*C*MF + B*MF = B*(C+1)*MF
    const int MF = out_size / (B * (C + 1));
    float* mask = out + (size_t)B * C * MF;

    int* cum = (int*)d_ws;  // B*TP ints = 128 KB scratch

    cumsum_k<<<B, 256, 0, stream>>>(dur, cum);

    dim3 ggrid((MF + 1023) / 1024, B, C / CHUNK);
    if ((MF & 3) == 0)
        gather_k<true><<<ggrid, 256, 0, stream>>>(x, cum, out, mask, MF);
    else
        gather_k<false><<<ggrid, 256, 0, stream>>>(x, cum, out, mask, MF);
}